// Round 13
// baseline (184.982 us; speedup 1.0000x reference)
//
#include <hip/hip_runtime.h>

// ---------------------------------------------------------------------------
// MultiHeadAttention forward, MI355X (gfx950).
// fp32->bf16 convert; Q/K/V projections (bf16 MFMA GEMM, Q scaled by
// 0.125*log2e); flash attention v8 (32x32x16 MFMA, split-KV x2: 8 waves =
// 4 q-groups x 2 kv-splits, 128-kv-row super-iters, in-register P via
// cvt_pk + permlane32_swap, l via ones-MFMA, defer-max, counted-vmcnt
// pipeline, end-of-loop pair combine); output projection.
// ---------------------------------------------------------------------------

#define D_MODEL 1024
#define NHEADS  16
#define DKH     64
#define SEQ     2048
#define BATCH   2
#define MTOT    (BATCH * SEQ)            // 4096 rows
#define XE      ((long)MTOT * D_MODEL)   // 4194304 elems
#define WE      ((long)D_MODEL * D_MODEL)
#define QSCALE  0.18033688011112042f     // 0.125 * log2(e): softmax in exp2 domain

typedef __attribute__((ext_vector_type(8)))  short short8v;   // 8 x bf16
typedef __attribute__((ext_vector_type(4)))  short short4v;   // 4 x bf16
typedef __attribute__((ext_vector_type(4)))  float f32x4;     // 16x16 C/D frag
typedef __attribute__((ext_vector_type(16))) float f32x16;    // 32x32 C/D frag

typedef __attribute__((address_space(1))) void as1_void;
typedef __attribute__((address_space(3))) void as3_void;

__device__ __forceinline__ void gload16(const void* g, void* l) {
    __builtin_amdgcn_global_load_lds((const as1_void*)g, (as3_void*)l, 16, 0, 0);
}

__device__ __forceinline__ unsigned short f2bf(float x) {
    unsigned int u = __float_as_uint(x);
    u += 0x7FFFu + ((u >> 16) & 1u);     // RNE
    return (unsigned short)(u >> 16);
}

// native v_exp_f32: computes 2^x (avoid __exp2f: glibc name collision)
__device__ __forceinline__ float fexp2(float x) {
    return __builtin_amdgcn_exp2f(x);
}

// hardware packed f32x2 -> bf16x2 (one VALU op for two converts)
__device__ __forceinline__ unsigned int cvt_pk_bf16(float lo, float hi) {
    unsigned int r;
    asm("v_cvt_pk_bf16_f32 %0, %1, %2" : "=v"(r) : "v"(lo), "v"(hi));
    return r;
}

// XOR swizzle for [rows][64 bf16] LDS tiles (128B rows).
__device__ __forceinline__ int swz_u(int row, int col) {
    int byte = (col << 1) ^ ((row & 7) << 4);
    return (row << 6) + (byte >> 1);
}

// Vt swizzle: slot bits from (d&6)|((d>>3)&1): write pairs and reads stay low-way.
__device__ __forceinline__ int swz_v(int d, int kv) {
    int slot = (d & 6) | ((d >> 3) & 1);
    int byte = (kv << 1) ^ (slot << 4);
    return (d << 6) + (byte >> 1);
}

// ---------------------------------------------------------------------------
// fp32 -> bf16 convert, 7 arrays in one launch (blockIdx.y selects array)
// ---------------------------------------------------------------------------
struct ConvArgs {
    const float*    src[7];
    unsigned short* dst[7];
    int             n4[7];
};

__global__ __launch_bounds__(256) void convert_kernel(ConvArgs a) {
    int z = blockIdx.y;
    const float4*   s = (const float4*)a.src[z];
    unsigned short* d = a.dst[z];
    int n = a.n4[z];
    for (int i = blockIdx.x * blockDim.x + threadIdx.x; i < n;
         i += gridDim.x * blockDim.x) {
        float4 v = s[i];
        ushort4 o;
        o.x = f2bf(v.x); o.y = f2bf(v.y); o.z = f2bf(v.z); o.w = f2bf(v.w);
        *(ushort4*)(d + 4L * i) = o;
    }
}

// ---------------------------------------------------------------------------
// GEMM: C[M,N] = A[M,K] * Bm[N,K]^T  (both K-major), + bias, * scale.
// 128x128 tile, BK=32, 4 waves (2x2), 16x16x32 bf16 MFMA, global_load_lds.
// ---------------------------------------------------------------------------
__device__ __forceinline__ void stv(float* p, float v)          { *p = v; }
__device__ __forceinline__ void stv(unsigned short* p, float v) { *p = f2bf(v); }

template <typename OutT>
__device__ __forceinline__ void gemm_core(const unsigned short* __restrict__ A,
                                          const unsigned short* __restrict__ Bm,
                                          const float* __restrict__ bias,
                                          OutT* __restrict__ C,
                                          int K, int N, float scale) {
    __shared__ unsigned short As[128 * 32];
    __shared__ unsigned short Bs[128 * 32];

    const int t    = threadIdx.x;
    const int lane = t & 63;
    const int w    = t >> 6;
    const int wm   = w >> 1, wn = w & 1;
    const int l15  = lane & 15, g = lane >> 4;
    const long m0  = (long)blockIdx.y * 128;
    const long n0  = (long)blockIdx.x * 128;

    f32x4 acc[4][4] = {};

    const int idx0 = t, idx1 = t + 256;
    const int r0 = idx0 >> 2, c0 = (idx0 & 3) * 8;
    const int r1 = idx1 >> 2, c1 = (idx1 & 3) * 8;
    const unsigned short* pa0 = A  + (m0 + r0) * K + c0;
    const unsigned short* pa1 = A  + (m0 + r1) * K + c1;
    const unsigned short* pb0 = Bm + (n0 + r0) * K + c0;
    const unsigned short* pb1 = Bm + (n0 + r1) * K + c1;

    for (int k0 = 0; k0 < K; k0 += 32) {
        gload16(pa0 + k0, &As[idx0 * 8]);
        gload16(pa1 + k0, &As[idx1 * 8]);
        gload16(pb0 + k0, &Bs[idx0 * 8]);
        gload16(pb1 + k0, &Bs[idx1 * 8]);
        __syncthreads();

        short8v af[4], bf_[4];
#pragma unroll
        for (int mf = 0; mf < 4; ++mf)
            af[mf] = *(const short8v*)&As[(wm * 64 + mf * 16 + l15) * 32 + g * 8];
#pragma unroll
        for (int nf = 0; nf < 4; ++nf)
            bf_[nf] = *(const short8v*)&Bs[(wn * 64 + nf * 16 + l15) * 32 + g * 8];
#pragma unroll
        for (int mf = 0; mf < 4; ++mf)
#pragma unroll
            for (int nf = 0; nf < 4; ++nf)
                acc[mf][nf] = __builtin_amdgcn_mfma_f32_16x16x32_bf16(
                    af[mf], bf_[nf], acc[mf][nf], 0, 0, 0);
        __syncthreads();
    }

    float bvv[4];
#pragma unroll
    for (int nf = 0; nf < 4; ++nf)
        bvv[nf] = bias[n0 + wn * 64 + nf * 16 + l15];

#pragma unroll
    for (int mf = 0; mf < 4; ++mf)
#pragma unroll
        for (int nf = 0; nf < 4; ++nf)
#pragma unroll
            for (int r = 0; r < 4; ++r) {
                long row = m0 + wm * 64 + mf * 16 + g * 4 + r;
                long col = n0 + wn * 64 + nf * 16 + l15;
                float v = (acc[mf][nf][r] + bvv[nf]) * scale;
                stv(C + row * (long)N + col, v);
            }
}

__global__ __launch_bounds__(256) void proj_kernel(
    const unsigned short* __restrict__ xb, const unsigned short* __restrict__ wb,
    const float* __restrict__ bq, const float* __restrict__ bk,
    const float* __restrict__ bv, unsigned short* __restrict__ qkv) {
    int z = blockIdx.z;
    const float* bias = (z == 0) ? bq : (z == 1) ? bk : bv;
    float scale = (z == 0) ? QSCALE : 1.0f;
    gemm_core<unsigned short>(xb + (long)z * XE, wb + (long)z * WE, bias,
                              qkv + (long)z * XE, D_MODEL, D_MODEL, scale);
}

__global__ __launch_bounds__(256) void out_kernel(
    const unsigned short* __restrict__ ob, const unsigned short* __restrict__ wo,
    const float* __restrict__ bo, float* __restrict__ out) {
    gemm_core<float>(ob, wo, bo, out, D_MODEL, D_MODEL, 1.0f);
}

// ---------------------------------------------------------------------------
// Flash attention v8: block = 128 q rows, one (b,h); 512 threads = 8 waves
// = 4 q-groups (32 q each) x 2 kv-splits. Super-iter j stages 128 kv rows
// (2 tile slots); wave (qg,sp) computes tile 2j+sp with v6's verified
// 32x32x16 body (swapped QK^T, in-register P, ones-MFMA l, defer-max).
// End: wave pairs combine partial (o, l, m) via LDS (aliased over K/V bufs
// after vmcnt(0) drain). 16 waves/CU vs v6's 8.
// ---------------------------------------------------------------------------
#define TSZ 4096   // elems per 64x64 tile slot
#define NTS 16     // super-iters (2048 / 128)

__global__ __launch_bounds__(512, 4) void attn_kernel(
    const unsigned short* __restrict__ Qb, const unsigned short* __restrict__ Kb,
    const unsigned short* __restrict__ Vb, unsigned short* __restrict__ Ob) {
    // manual layout: K/V double-buffered chunks + corrS + mS; combine area
    // aliases the K/V region after the loop (guarded by vmcnt(0) + barrier).
    __shared__ alignas(16) unsigned char SM[67584];
    unsigned short* KsB  = (unsigned short*)SM;            // [2 dbuf][2 tile][TSZ]
    unsigned short* VtB  = (unsigned short*)(SM + 32768);  // [2 dbuf][2 tile][TSZ]
    float*          corrS = (float*)(SM + 65536);          // [8 waves][32]
    float*          mS    = (float*)(SM + 66560);          // [2 sp][4 qg][32]
    float*          comb  = (float*)SM;                    // 48x4x64 floats (48KB)

    const int t = threadIdx.x, lane = t & 63, w = t >> 6;
    const int l31 = lane & 31, h = lane >> 5;
    const int qg = w & 3, sp = w >> 2;
    const int bh = blockIdx.y;
    const long headoff = (long)(bh >> 4) * SEQ * D_MODEL + (long)(bh & 15) * DKH;
    const int q0w = blockIdx.x * 128 + qg * 32;

    // Q rows -> B-frag registers: N-col = q = l31, k-elems d = step*16+h*8+j
    short8v qf[4];
#pragma unroll
    for (int step = 0; step < 4; ++step)
        qf[step] = *(const short8v*)(Qb + headoff +
            (long)(q0w + l31) * D_MODEL + step * 16 + h * 8);

    short8v onesv;
#pragma unroll
    for (int j = 0; j < 8; ++j) onesv[j] = (short)0x3F80;   // bf16 1.0

    f32x16 o[2] = {};        // O cols d = db*32+l31; rows q = (r&3)+8(r>>2)+4h
    f32x16 ol = {};          // l accumulator, same row layout
    float mrun = -3.0e38f;

    // V staging: 512 threads cover 2 tiles; t<256 -> tile 0, else tile 1
    const int vtile = t >> 8, t8 = t & 255;
    const int vd0  = (t8 & 31) * 2;
    const int vkv0 = (t8 >> 5) * 8;
    // K staging: one gload16 per tile per thread
    const int kr0 = t >> 3, ks0 = t & 7;

    unsigned int va[8];   // in-flight V gather regs

#define ISSUE_V(kt)                                                        \
    _Pragma("unroll")                                                      \
    for (int j = 0; j < 8; ++j)                                            \
        va[j] = *(const unsigned int*)(Vb + headoff +                      \
            (long)((kt) + vtile * 64 + vkv0 + j) * D_MODEL + vd0);

#define ISSUE_K(kt, dbuf)                                                  \
    gload16(Kb + headoff + (long)((kt) + kr0) * D_MODEL +                  \
                ((ks0 ^ (kr0 & 7)) << 3),                                  \
            &KsB[((dbuf) * 2 + 0) * TSZ + t * 8]);                         \
    gload16(Kb + headoff + (long)((kt) + 64 + kr0) * D_MODEL +             \
                ((ks0 ^ (kr0 & 7)) << 3),                                  \
            &KsB[((dbuf) * 2 + 1) * TSZ + t * 8]);

#define WRITE_V(dbuf)                                                      \
    {                                                                      \
        short8v ra, rb;                                                    \
        _Pragma("unroll")                                                  \
        for (int j = 0; j < 8; ++j) {                                      \
            ra[j] = (short)(va[j] & 0xffffu);                              \
            rb[j] = (short)(va[j] >> 16);                                  \
        }                                                                  \
        unsigned short* vt = &VtB[((dbuf) * 2 + vtile) * TSZ];             \
        *(short8v*)&vt[swz_v(vd0,     vkv0)] = ra;                         \
        *(short8v*)&vt[swz_v(vd0 + 1, vkv0)] = rb;                         \
    }

    // ---- prologue: drain Q loads, stage chunk 0 (tiles 0,1) ----
    asm volatile("s_waitcnt vmcnt(0)" ::: "memory");
    ISSUE_V(0);
    ISSUE_K(0, 0);
    WRITE_V(0);              // compiler waits va; K stays in flight
    int cur = 0;

    for (int it = 0; it < NTS; ++it) {
        const int nxt = cur ^ 1;
        const int ktn = ((it + 1) & (NTS - 1)) * 128;   // wrapped prefetch
        ISSUE_V(ktn);
        ISSUE_K(ktn, nxt);
        // outstanding: K(cur)=2 + V(nxt)=8 + K(nxt)=2 = 12; complete oldest 2
        asm volatile("s_waitcnt vmcnt(10)" ::: "memory");
        asm volatile("s_waitcnt lgkmcnt(0)" ::: "memory");
        __builtin_amdgcn_sched_barrier(0);
        __builtin_amdgcn_s_barrier();
        __builtin_amdgcn_sched_barrier(0);

        const int kO = (cur * 2 + sp) * TSZ;   // this wave's tile slot

        // ---- S^T = K * Q^T : st[b] covers kv-block b (32 kv x 32 q) ----
        f32x16 st[2] = {};
        __builtin_amdgcn_s_setprio(1);
#pragma unroll
        for (int step = 0; step < 4; ++step) {
            short8v kf0 = *(const short8v*)&KsB[kO + swz_u(l31,      step * 16 + h * 8)];
            st[0] = __builtin_amdgcn_mfma_f32_32x32x16_bf16(kf0, qf[step], st[0], 0, 0, 0);
            short8v kf1 = *(const short8v*)&KsB[kO + swz_u(32 + l31, step * 16 + h * 8)];
            st[1] = __builtin_amdgcn_mfma_f32_32x32x16_bf16(kf1, qf[step], st[1], 0, 0, 0);
        }
        __builtin_amdgcn_s_setprio(0);

        // ---- softmax: max3-tree reduce, defer-max THR=8, exp2 domain ----
        float m01[8];
#pragma unroll
        for (int j = 0; j < 8; ++j)
            m01[j] = fmaxf(fmaxf(st[0][2 * j], st[0][2 * j + 1]),
                           fmaxf(st[1][2 * j], st[1][2 * j + 1]));
        float vmax = fmaxf(fmaxf(fmaxf(fmaxf(m01[0], m01[1]), m01[2]),
                                 fmaxf(fmaxf(m01[3], m01[4]), m01[5])),
                           fmaxf(m01[6], m01[7]));
        vmax = fmaxf(vmax, __shfl_xor(vmax, 32));

        const bool grow = __any(vmax > mrun + 8.0f);
        if (grow) {
            float mnew = fmaxf(mrun, vmax);
            float corr = fexp2(mrun - mnew);
            mrun = mnew;
            if (lane < 32) corrS[w * 32 + l31] = corr;
#pragma unroll
            for (int q2 = 0; q2 < 4; ++q2) {
                float4 cv = *(const float4*)&corrS[w * 32 + q2 * 8 + h * 4];
#pragma unroll
                for (int r3 = 0; r3 < 4; ++r3) {
                    o[0][q2 * 4 + r3] *= cv[r3];
                    o[1][q2 * 4 + r3] *= cv[r3];
                    ol[q2 * 4 + r3]   *= cv[r3];
                }
            }
        }

#pragma unroll
        for (int b = 0; b < 2; ++b)
#pragma unroll
            for (int r = 0; r < 16; ++r)
                st[b][r] = fexp2(st[b][r] - mrun);

        // ---- PV: in-register P (cvt_pk + permlane32_swap), no LDS ----
        __builtin_amdgcn_s_setprio(1);
#pragma unroll
        for (int b = 0; b < 2; ++b)
#pragma unroll
            for (int s = 0; s < 2; ++s) {
                unsigned int u  = cvt_pk_bf16(st[b][s * 8 + 0], st[b][s * 8 + 1]);
                unsigned int u2 = cvt_pk_bf16(st[b][s * 8 + 2], st[b][s * 8 + 3]);
                unsigned int v  = cvt_pk_bf16(st[b][s * 8 + 4], st[b][s * 8 + 5]);
                unsigned int v2 = cvt_pk_bf16(st[b][s * 8 + 6], st[b][s * 8 + 7]);
                asm("v_permlane32_swap_b32 %0, %1" : "+v"(u),  "+v"(v));
                asm("v_permlane32_swap_b32 %0, %1" : "+v"(u2), "+v"(v2));
                uint4 pu = {u, u2, v, v2};
                short8v pa = __builtin_bit_cast(short8v, pu);
                ol = __builtin_amdgcn_mfma_f32_32x32x16_bf16(pa, onesv, ol, 0, 0, 0);
                short8v vb0 = *(const short8v*)&VtB[kO + swz_v(l31,      b * 32 + s * 16 + h * 8)];
                o[0] = __builtin_amdgcn_mfma_f32_32x32x16_bf16(pa, vb0, o[0], 0, 0, 0);
                short8v vb1 = *(const short8v*)&VtB[kO + swz_v(32 + l31, b * 32 + s * 16 + h * 8)];
                o[1] = __builtin_amdgcn_mfma_f32_32x32x16_bf16(pa, vb1, o[1], 0, 0, 0);
            }
        __builtin_amdgcn_s_setprio(0);

        // ---- write next chunk's V (regs arrived; compiler waits vmcnt) ----
        WRITE_V(nxt);
        cur = nxt;
    }

    // ---- drain stray K gloads before aliasing SM with combine area ----
    asm volatile("s_waitcnt vmcnt(0)" ::: "memory");

    // ---- split-KV pair combine: (qg, sp=0) += (qg, sp=1) ----
    if (lane < 32) mS[(sp * 4 + qg) * 32 + l31] = mrun;
    __syncthreads();   // all PV reads of K/V done; mS visible

    // rescale own partials to the pair max (per o-row q = q2*8 + h*4 + r3)
#pragma unroll
    for (int q2 = 0; q2 < 4; ++q2) {
        float4 ma = *(const float4*)&mS[(0 * 4 + qg) * 32 + q2 * 8 + h * 4];
        float4 mb = *(const float4*)&mS[(1 * 4 + qg) * 32 + q2 * 8 + h * 4];
#pragma unroll
        for (int r3 = 0; r3 < 4; ++r3) {
            float mt = fmaxf(ma[r3], mb[r3]);
            float mo = (sp == 0) ? ma[r3] : mb[r3];
            float sc = fexp2(mo - mt);
            o[0][q2 * 4 + r3] *= sc;
            o[1][q2 * 4 + r3] *= sc;
            ol[q2 * 4 + r3]   *= sc;
        }
    }

    // sp=1 ships 48 floats/lane; layout [c:48][qg:4][lane:64] (2-way banks)
    if (sp == 1) {
#pragma unroll
        for (int c = 0; c < 16; ++c) {
            comb[((c)      * 4 + qg) * 64 + lane] = o[0][c];
            comb[((c + 16) * 4 + qg) * 64 + lane] = o[1][c];
            comb[((c + 32) * 4 + qg) * 64 + lane] = ol[c];
        }
    }
    __syncthreads();
    if (sp == 0) {
#pragma unroll
        for (int c = 0; c < 16; ++c) {
            o[0][c] += comb[((c)      * 4 + qg) * 64 + lane];
            o[1][c] += comb[((c + 16) * 4 + qg) * 64 + lane];
            ol[c]   += comb[((c + 32) * 4 + qg) * 64 + lane];
        }
        // ---- epilogue: O /= l ----
#pragma unroll
        for (int q2 = 0; q2 < 4; ++q2)
#pragma unroll
            for (int r3 = 0; r3 < 4; ++r3) {
                float inv = 1.f / (ol[q2 * 4 + r3] + 1e-9f);
                long rowoff = headoff +
                    (long)(q0w + q2 * 8 + h * 4 + r3) * D_MODEL;
                Ob[rowoff + l31]      = f2bf(o[0][q2 * 4 + r3] * inv);
                Ob[rowoff + 32 + l31] = f2bf(o[1][q2 * 4 + r3] * inv);
            }
    }
#undef ISSUE_V
#undef ISSUE_K
#undef WRITE_V
}

// ---------------------------------------------------------------------------
// Launch
// ---------------------------------------------------------------------------
extern "C" void kernel_launch(void* const* d_in, const int* in_sizes, int n_in,
                              void* d_out, int out_size, void* d_ws, size_t ws_size,
                              hipStream_t stream) {
    // d_in order: 0 q, 1 k, 2 v, 3 Wq, 4 bq, 5 Wk, 6 bk, 7 Wv, 8 bv, 9 Wo, 10 bo
    unsigned short* ws  = (unsigned short*)d_ws;
    unsigned short* xb  = ws;                       // 3*XE  bf16 inputs q,k,v
    unsigned short* wb  = ws + 3L * XE;             // 4*WE  bf16 weights
    unsigned short* qkv = ws + 3L * XE + 4L * WE;   // 3*XE  Q(scaled), K, V
    unsigned short* ob  = qkv + 3L * XE;            // XE    attention output

    ConvArgs ca;
    ca.src[0] = (const float*)d_in[0]; ca.dst[0] = xb;           ca.n4[0] = (int)(XE / 4);
    ca.src[1] = (const float*)d_in[1]; ca.dst[1] = xb + XE;      ca.n4[1] = (int)(XE / 4);
    ca.src[2] = (const float*)d_in[2]; ca.dst[2] = xb + 2L * XE; ca.n4[2] = (int)(XE / 4);
    ca.src[3] = (const float*)d_in[3]; ca.dst[3] = wb;           ca.n4[3] = (int)(WE / 4);
    ca.src[4] = (const float*)d_in[5]; ca.dst[4] = wb + WE;      ca.n4[4] = (int)(WE / 4);
    ca.src[5] = (const float*)d_in[7]; ca.dst[5] = wb + 2L * WE; ca.n4[5] = (int)(WE / 4);
    ca.src[6] = (const float*)d_in[9]; ca.dst[6] = wb + 3L * WE; ca.n4[6] = (int)(WE / 4);

    hipLaunchKernelGGL(convert_kernel, dim3(512, 7), dim3(256), 0, stream, ca);

    hipLaunchKernelGGL(proj_kernel, dim3(8, 32, 3), dim3(256), 0, stream,
                       xb, wb, (const float*)d_in[4], (const float*)d_in[6],
                       (const float*)d_in[8], qkv);

    hipLaunchKernelGGL(attn_kernel, dim3(16, 32), dim3(512), 0, stream,
                       qkv, qkv + XE, qkv + 2L * XE, ob);

    hipLaunchKernelGGL(out_kernel, dim3(8, 32), dim3(256), 0, stream,
                       ob, wb + 3L * WE, (const float*)d_in[10], (float*)d_out);
}

// Round 14
// 142.194 us; speedup vs baseline: 1.3009x; 1.3009x over previous
//
#include <hip/hip_runtime.h>

// ---------------------------------------------------------------------------
// MultiHeadAttention forward, MI355X (gfx950).
// fp32->bf16 convert; Q/K/V projections (bf16 MFMA GEMM, Q scaled by
// 0.125*log2e); flash attention v8b (32x32x16 MFMA, split-KV x2: 8 waves =
// 4 q-groups x 2 kv-splits, in-register P via cvt_pk + permlane32_swap,
// scalar lane-local l, defer-max, counted-vmcnt pipeline, end pair-combine);
// output projection.
// ---------------------------------------------------------------------------

#define D_MODEL 1024
#define NHEADS  16
#define DKH     64
#define SEQ     2048
#define BATCH   2
#define MTOT    (BATCH * SEQ)            // 4096 rows
#define XE      ((long)MTOT * D_MODEL)   // 4194304 elems
#define WE      ((long)D_MODEL * D_MODEL)
#define QSCALE  0.18033688011112042f     // 0.125 * log2(e): softmax in exp2 domain

typedef __attribute__((ext_vector_type(8)))  short short8v;   // 8 x bf16
typedef __attribute__((ext_vector_type(4)))  short short4v;   // 4 x bf16
typedef __attribute__((ext_vector_type(4)))  float f32x4;     // 16x16 C/D frag
typedef __attribute__((ext_vector_type(16))) float f32x16;    // 32x32 C/D frag

typedef __attribute__((address_space(1))) void as1_void;
typedef __attribute__((address_space(3))) void as3_void;

__device__ __forceinline__ void gload16(const void* g, void* l) {
    __builtin_amdgcn_global_load_lds((const as1_void*)g, (as3_void*)l, 16, 0, 0);
}

__device__ __forceinline__ unsigned short f2bf(float x) {
    unsigned int u = __float_as_uint(x);
    u += 0x7FFFu + ((u >> 16) & 1u);     // RNE
    return (unsigned short)(u >> 16);
}

// native v_exp_f32: computes 2^x (avoid __exp2f: glibc name collision)
__device__ __forceinline__ float fexp2(float x) {
    return __builtin_amdgcn_exp2f(x);
}

// hardware packed f32x2 -> bf16x2 (one VALU op for two converts)
__device__ __forceinline__ unsigned int cvt_pk_bf16(float lo, float hi) {
    unsigned int r;
    asm("v_cvt_pk_bf16_f32 %0, %1, %2" : "=v"(r) : "v"(lo), "v"(hi));
    return r;
}

// XOR swizzle for [rows][64 bf16] LDS tiles (128B rows).
__device__ __forceinline__ int swz_u(int row, int col) {
    int byte = (col << 1) ^ ((row & 7) << 4);
    return (row << 6) + (byte >> 1);
}

// Vt swizzle: slot bits from (d&6)|((d>>3)&1): write pairs and reads stay low-way.
__device__ __forceinline__ int swz_v(int d, int kv) {
    int slot = (d & 6) | ((d >> 3) & 1);
    int byte = (kv << 1) ^ (slot << 4);
    return (d << 6) + (byte >> 1);
}

// ---------------------------------------------------------------------------
// fp32 -> bf16 convert, 7 arrays in one launch (blockIdx.y selects array)
// ---------------------------------------------------------------------------
struct ConvArgs {
    const float*    src[7];
    unsigned short* dst[7];
    int             n4[7];
};

__global__ __launch_bounds__(256) void convert_kernel(ConvArgs a) {
    int z = blockIdx.y;
    const float4*   s = (const float4*)a.src[z];
    unsigned short* d = a.dst[z];
    int n = a.n4[z];
    for (int i = blockIdx.x * blockDim.x + threadIdx.x; i < n;
         i += gridDim.x * blockDim.x) {
        float4 v = s[i];
        ushort4 o;
        o.x = f2bf(v.x); o.y = f2bf(v.y); o.z = f2bf(v.z); o.w = f2bf(v.w);
        *(ushort4*)(d + 4L * i) = o;
    }
}

// ---------------------------------------------------------------------------
// GEMM: C[M,N] = A[M,K] * Bm[N,K]^T  (both K-major), + bias, * scale.
// 128x128 tile, BK=32, 4 waves (2x2), 16x16x32 bf16 MFMA, global_load_lds.
// ---------------------------------------------------------------------------
__device__ __forceinline__ void stv(float* p, float v)          { *p = v; }
__device__ __forceinline__ void stv(unsigned short* p, float v) { *p = f2bf(v); }

template <typename OutT>
__device__ __forceinline__ void gemm_core(const unsigned short* __restrict__ A,
                                          const unsigned short* __restrict__ Bm,
                                          const float* __restrict__ bias,
                                          OutT* __restrict__ C,
                                          int K, int N, float scale) {
    __shared__ unsigned short As[128 * 32];
    __shared__ unsigned short Bs[128 * 32];

    const int t    = threadIdx.x;
    const int lane = t & 63;
    const int w    = t >> 6;
    const int wm   = w >> 1, wn = w & 1;
    const int l15  = lane & 15, g = lane >> 4;
    const long m0  = (long)blockIdx.y * 128;
    const long n0  = (long)blockIdx.x * 128;

    f32x4 acc[4][4] = {};

    const int idx0 = t, idx1 = t + 256;
    const int r0 = idx0 >> 2, c0 = (idx0 & 3) * 8;
    const int r1 = idx1 >> 2, c1 = (idx1 & 3) * 8;
    const unsigned short* pa0 = A  + (m0 + r0) * K + c0;
    const unsigned short* pa1 = A  + (m0 + r1) * K + c1;
    const unsigned short* pb0 = Bm + (n0 + r0) * K + c0;
    const unsigned short* pb1 = Bm + (n0 + r1) * K + c1;

    for (int k0 = 0; k0 < K; k0 += 32) {
        gload16(pa0 + k0, &As[idx0 * 8]);
        gload16(pa1 + k0, &As[idx1 * 8]);
        gload16(pb0 + k0, &Bs[idx0 * 8]);
        gload16(pb1 + k0, &Bs[idx1 * 8]);
        __syncthreads();

        short8v af[4], bf_[4];
#pragma unroll
        for (int mf = 0; mf < 4; ++mf)
            af[mf] = *(const short8v*)&As[(wm * 64 + mf * 16 + l15) * 32 + g * 8];
#pragma unroll
        for (int nf = 0; nf < 4; ++nf)
            bf_[nf] = *(const short8v*)&Bs[(wn * 64 + nf * 16 + l15) * 32 + g * 8];
#pragma unroll
        for (int mf = 0; mf < 4; ++mf)
#pragma unroll
            for (int nf = 0; nf < 4; ++nf)
                acc[mf][nf] = __builtin_amdgcn_mfma_f32_16x16x32_bf16(
                    af[mf], bf_[nf], acc[mf][nf], 0, 0, 0);
        __syncthreads();
    }

    float bvv[4];
#pragma unroll
    for (int nf = 0; nf < 4; ++nf)
        bvv[nf] = bias[n0 + wn * 64 + nf * 16 + l15];

#pragma unroll
    for (int mf = 0; mf < 4; ++mf)
#pragma unroll
        for (int nf = 0; nf < 4; ++nf)
#pragma unroll
            for (int r = 0; r < 4; ++r) {
                long row = m0 + wm * 64 + mf * 16 + g * 4 + r;
                long col = n0 + wn * 64 + nf * 16 + l15;
                float v = (acc[mf][nf][r] + bvv[nf]) * scale;
                stv(C + row * (long)N + col, v);
            }
}

__global__ __launch_bounds__(256) void proj_kernel(
    const unsigned short* __restrict__ xb, const unsigned short* __restrict__ wb,
    const float* __restrict__ bq, const float* __restrict__ bk,
    const float* __restrict__ bv, unsigned short* __restrict__ qkv) {
    int z = blockIdx.z;
    const float* bias = (z == 0) ? bq : (z == 1) ? bk : bv;
    float scale = (z == 0) ? QSCALE : 1.0f;
    gemm_core<unsigned short>(xb + (long)z * XE, wb + (long)z * WE, bias,
                              qkv + (long)z * XE, D_MODEL, D_MODEL, scale);
}

__global__ __launch_bounds__(256) void out_kernel(
    const unsigned short* __restrict__ ob, const unsigned short* __restrict__ wo,
    const float* __restrict__ bo, float* __restrict__ out) {
    gemm_core<float>(ob, wo, bo, out, D_MODEL, D_MODEL, 1.0f);
}

// ---------------------------------------------------------------------------
// Flash attention v8b: block = 128 q rows, one (b,h); 512 threads = 8 waves
// = 4 q-groups (32 q each) x 2 kv-splits. Super-iter j stages 128 kv rows
// (2 tile slots); wave (qg,sp) computes tile 2j+sp (32x32x16 body, swapped
// QK^T, in-register P, defer-max). l = scalar per-lane row-sum (q = l31
// domain; 31 adds + shfl_xor(32)/iter), redistributed once at the combine.
// NO launch-bounds VGPR clamp (v8's 64-reg spill was the regression).
// ---------------------------------------------------------------------------
#define TSZ 4096   // elems per 64x64 tile slot
#define NTS 16     // super-iters (2048 / 128)

__global__ __launch_bounds__(512) void attn_kernel(
    const unsigned short* __restrict__ Qb, const unsigned short* __restrict__ Kb,
    const unsigned short* __restrict__ Vb, unsigned short* __restrict__ Ob) {
    // layout: K/V double-buffered chunks, then corrS/mS/lS/lTot; the o-combine
    // area aliases the Ks region after the loop (guarded by vmcnt(0)+barrier).
    __shared__ alignas(16) unsigned char SM[69120];
    unsigned short* KsB   = (unsigned short*)SM;            // [2 dbuf][2 tile][TSZ]
    unsigned short* VtB   = (unsigned short*)(SM + 32768);  // [2 dbuf][2 tile][TSZ]
    float*          corrS = (float*)(SM + 65536);           // [8 waves][32]
    float*          mS    = (float*)(SM + 66560);           // [2 sp][4 qg][32]
    float*          lS    = (float*)(SM + 67584);           // [2 sp][4 qg][32]
    float*          lTot  = (float*)(SM + 68608);           // [4 qg][32]
    float*          comb  = (float*)SM;                     // 32x4x64 f32 = 32 KB

    const int t = threadIdx.x, lane = t & 63, w = t >> 6;
    const int l31 = lane & 31, h = lane >> 5;
    const int qg = w & 3, sp = w >> 2;
    const int bh = blockIdx.y;
    const long headoff = (long)(bh >> 4) * SEQ * D_MODEL + (long)(bh & 15) * DKH;
    const int q0w = blockIdx.x * 128 + qg * 32;

    // Q rows -> B-frag registers: N-col = q = l31, k-elems d = step*16+h*8+j
    short8v qf[4];
#pragma unroll
    for (int step = 0; step < 4; ++step)
        qf[step] = *(const short8v*)(Qb + headoff +
            (long)(q0w + l31) * D_MODEL + step * 16 + h * 8);

    f32x16 o[2] = {};        // O cols d = db*32+l31; rows q = (r&3)+8(r>>2)+4h
    float mrun = -3.0e38f;   // running max, q = l31 domain
    float lrun = 0.f;        // running denom, q = l31 domain

    // V staging: 512 threads cover 2 tiles; t<256 -> tile 0, else tile 1
    const int vtile = t >> 8, t8 = t & 255;
    const int vd0  = (t8 & 31) * 2;
    const int vkv0 = (t8 >> 5) * 8;
    // K staging: one gload16 per tile per thread
    const int kr0 = t >> 3, ks0 = t & 7;

    unsigned int va[8];   // in-flight V gather regs

#define ISSUE_V(kt)                                                        \
    _Pragma("unroll")                                                      \
    for (int j = 0; j < 8; ++j)                                            \
        va[j] = *(const unsigned int*)(Vb + headoff +                      \
            (long)((kt) + vtile * 64 + vkv0 + j) * D_MODEL + vd0);

#define ISSUE_K(kt, dbuf)                                                  \
    gload16(Kb + headoff + (long)((kt) + kr0) * D_MODEL +                  \
                ((ks0 ^ (kr0 & 7)) << 3),                                  \
            &KsB[((dbuf) * 2 + 0) * TSZ + t * 8]);                         \
    gload16(Kb + headoff + (long)((kt) + 64 + kr0) * D_MODEL +             \
                ((ks0 ^ (kr0 & 7)) << 3),                                  \
            &KsB[((dbuf) * 2 + 1) * TSZ + t * 8]);

#define WRITE_V(dbuf)                                                      \
    {                                                                      \
        short8v ra, rb;                                                    \
        _Pragma("unroll")                                                  \
        for (int j = 0; j < 8; ++j) {                                      \
            ra[j] = (short)(va[j] & 0xffffu);                              \
            rb[j] = (short)(va[j] >> 16);                                  \
        }                                                                  \
        unsigned short* vt = &VtB[((dbuf) * 2 + vtile) * TSZ];             \
        *(short8v*)&vt[swz_v(vd0,     vkv0)] = ra;                         \
        *(short8v*)&vt[swz_v(vd0 + 1, vkv0)] = rb;                         \
    }

    // ---- prologue: drain Q loads, stage chunk 0 (tiles 0,1) ----
    asm volatile("s_waitcnt vmcnt(0)" ::: "memory");
    ISSUE_V(0);
    ISSUE_K(0, 0);
    WRITE_V(0);              // compiler waits va; K stays in flight
    int cur = 0;

    for (int it = 0; it < NTS; ++it) {
        const int nxt = cur ^ 1;
        const int ktn = ((it + 1) & (NTS - 1)) * 128;   // wrapped prefetch
        ISSUE_V(ktn);
        ISSUE_K(ktn, nxt);
        // outstanding: K(cur)=2 + V(nxt)=8 + K(nxt)=2 = 12; complete oldest 2
        asm volatile("s_waitcnt vmcnt(10)" ::: "memory");
        asm volatile("s_waitcnt lgkmcnt(0)" ::: "memory");
        __builtin_amdgcn_sched_barrier(0);
        __builtin_amdgcn_s_barrier();
        __builtin_amdgcn_sched_barrier(0);

        const int kO = (cur * 2 + sp) * TSZ;   // this wave's tile slot

        // ---- S^T = K * Q^T : st[b] covers kv-block b (32 kv x 32 q) ----
        f32x16 st[2] = {};
        __builtin_amdgcn_s_setprio(1);
#pragma unroll
        for (int step = 0; step < 4; ++step) {
            short8v kf0 = *(const short8v*)&KsB[kO + swz_u(l31,      step * 16 + h * 8)];
            st[0] = __builtin_amdgcn_mfma_f32_32x32x16_bf16(kf0, qf[step], st[0], 0, 0, 0);
            short8v kf1 = *(const short8v*)&KsB[kO + swz_u(32 + l31, step * 16 + h * 8)];
            st[1] = __builtin_amdgcn_mfma_f32_32x32x16_bf16(kf1, qf[step], st[1], 0, 0, 0);
        }
        __builtin_amdgcn_s_setprio(0);

        // ---- softmax: max3-tree reduce, defer-max THR=8, exp2 domain ----
        float m01[8];
#pragma unroll
        for (int j = 0; j < 8; ++j)
            m01[j] = fmaxf(fmaxf(st[0][2 * j], st[0][2 * j + 1]),
                           fmaxf(st[1][2 * j], st[1][2 * j + 1]));
        float vmax = fmaxf(fmaxf(fmaxf(fmaxf(m01[0], m01[1]), m01[2]),
                                 fmaxf(fmaxf(m01[3], m01[4]), m01[5])),
                           fmaxf(m01[6], m01[7]));
        vmax = fmaxf(vmax, __shfl_xor(vmax, 32));

        const bool grow = __any(vmax > mrun + 8.0f);
        if (grow) {
            float mnew = fmaxf(mrun, vmax);
            float corr = fexp2(mrun - mnew);
            mrun = mnew;
            lrun *= corr;                       // scalar, q = l31 domain
            if (lane < 32) corrS[w * 32 + l31] = corr;
#pragma unroll
            for (int q2 = 0; q2 < 4; ++q2) {
                float4 cv = *(const float4*)&corrS[w * 32 + q2 * 8 + h * 4];
#pragma unroll
                for (int r3 = 0; r3 < 4; ++r3) {
                    o[0][q2 * 4 + r3] *= cv[r3];
                    o[1][q2 * 4 + r3] *= cv[r3];
                }
            }
        }

        float ps = 0.f;
#pragma unroll
        for (int b = 0; b < 2; ++b)
#pragma unroll
            for (int r = 0; r < 16; ++r) {
                st[b][r] = fexp2(st[b][r] - mrun);
                ps += st[b][r];
            }
        ps += __shfl_xor(ps, 32);               // both kv-halves -> full sum
        lrun += ps;

        // ---- PV: in-register P (cvt_pk + permlane32_swap), no LDS ----
        __builtin_amdgcn_s_setprio(1);
#pragma unroll
        for (int b = 0; b < 2; ++b)
#pragma unroll
            for (int s = 0; s < 2; ++s) {
                unsigned int u  = cvt_pk_bf16(st[b][s * 8 + 0], st[b][s * 8 + 1]);
                unsigned int u2 = cvt_pk_bf16(st[b][s * 8 + 2], st[b][s * 8 + 3]);
                unsigned int v  = cvt_pk_bf16(st[b][s * 8 + 4], st[b][s * 8 + 5]);
                unsigned int v2 = cvt_pk_bf16(st[b][s * 8 + 6], st[b][s * 8 + 7]);
                asm("v_permlane32_swap_b32 %0, %1" : "+v"(u),  "+v"(v));
                asm("v_permlane32_swap_b32 %0, %1" : "+v"(u2), "+v"(v2));
                uint4 pu = {u, u2, v, v2};
                short8v pa = __builtin_bit_cast(short8v, pu);
                short8v vb0 = *(const short8v*)&VtB[kO + swz_v(l31,      b * 32 + s * 16 + h * 8)];
                o[0] = __builtin_amdgcn_mfma_f32_32x32x16_bf16(pa, vb0, o[0], 0, 0, 0);
                short8v vb1 = *(const short8v*)&VtB[kO + swz_v(32 + l31, b * 32 + s * 16 + h * 8)];
                o[1] = __builtin_amdgcn_mfma_f32_32x32x16_bf16(pa, vb1, o[1], 0, 0, 0);
            }
        __builtin_amdgcn_s_setprio(0);

        // ---- write next chunk's V (regs arrived; compiler waits vmcnt) ----
        WRITE_V(nxt);
        cur = nxt;
    }

    // ---- drain stray K gloads before aliasing SM with combine area ----
    asm volatile("s_waitcnt vmcnt(0)" ::: "memory");

    // ---- split-KV pair combine: (qg, sp=0) += (qg, sp=1) ----
    if (lane < 32) {
        mS[(sp * 4 + qg) * 32 + l31] = mrun;
        lS[(sp * 4 + qg) * 32 + l31] = lrun;
    }
    __syncthreads();   // all K/V reads done; mS/lS visible

    // rescale own o to the pair max (per o-row q = q2*8 + h*4 + r3)
#pragma unroll
    for (int q2 = 0; q2 < 4; ++q2) {
        float4 ma = *(const float4*)&mS[(0 * 4 + qg) * 32 + q2 * 8 + h * 4];
        float4 mb = *(const float4*)&mS[(1 * 4 + qg) * 32 + q2 * 8 + h * 4];
#pragma unroll
        for (int r3 = 0; r3 < 4; ++r3) {
            float mt = fmaxf(ma[r3], mb[r3]);
            float mo = (sp == 0) ? ma[r3] : mb[r3];
            float sc = fexp2(mo - mt);
            o[0][q2 * 4 + r3] *= sc;
            o[1][q2 * 4 + r3] *= sc;
        }
    }

    // sp=1 ships 32 floats/lane; layout [c:32][qg:4][lane:64] (aliases Ks)
    if (sp == 1) {
#pragma unroll
        for (int c = 0; c < 16; ++c) {
            comb[(c)        * 256 + qg * 64 + lane] = o[0][c];
            comb[(c + 16)   * 256 + qg * 64 + lane] = o[1][c];
        }
    }
    __syncthreads();
    if (sp == 0) {
#pragma unroll
        for (int c = 0; c < 16; ++c) {
            o[0][c] += comb[(c)      * 256 + qg * 64 + lane];
            o[1][c] += comb[(c + 16) * 256 + qg * 64 + lane];
        }
        // combined denom in q = l31 domain, redistribute via lTot
        float m0 = mS[(0 * 4 + qg) * 32 + l31];
        float m1 = mS[(1 * 4 + qg) * 32 + l31];
        float mt = fmaxf(m0, m1);
        float lt = lS[(0 * 4 + qg) * 32 + l31] * fexp2(m0 - mt) +
                   lS[(1 * 4 + qg) * 32 + l31] * fexp2(m1 - mt);
        if (lane < 32) lTot[qg * 32 + l31] = lt;
        // in-wave DS ordering: our own lTot writes are visible to our reads
        // ---- epilogue: O /= l ----
#pragma unroll
        for (int q2 = 0; q2 < 4; ++q2)
#pragma unroll
            for (int r3 = 0; r3 < 4; ++r3) {
                float inv = 1.f / (lTot[qg * 32 + q2 * 8 + h * 4 + r3] + 1e-9f);
                long rowoff = headoff +
                    (long)(q0w + q2 * 8 + h * 4 + r3) * D_MODEL;
                Ob[rowoff + l31]      = f2bf(o[0][q2 * 4 + r3] * inv);
                Ob[rowoff + 32 + l31] = f2bf(o[1][q2 * 4 + r3] * inv);
            }
    }
#undef ISSUE_V
#undef ISSUE_K
#undef WRITE_V
}

// ---------------------------------------------------------------------------
// Launch
// ---------------------------------------------------------------------------
extern "C" void kernel_launch(void* const* d_in, const int* in_sizes, int n_in,
                              void* d_out, int out_size, void* d_ws, size_t ws_size,
                              hipStream_t stream) {
    // d_in order: 0 q, 1 k, 2 v, 3 Wq, 4 bq, 5 Wk, 6 bk, 7 Wv, 8 bv, 9 Wo, 10 bo
    unsigned short* ws  = (unsigned short*)d_ws;
    unsigned short* xb  = ws;                       // 3*XE  bf16 inputs q,k,v
    unsigned short* wb  = ws + 3L * XE;             // 4*WE  bf16 weights
    unsigned short* qkv = ws + 3L * XE + 4L * WE;   // 3*XE  Q(scaled), K, V
    unsigned short* ob  = qkv + 3L * XE;            // XE    attention output

    ConvArgs ca;
    ca.src[0] = (const float*)d_in[0]; ca.dst[0] = xb;           ca.n4[0] = (int)(XE / 4);
    ca.src[1] = (const float*)d_in[1]; ca.dst[1] = xb + XE;      ca.n4[1] = (int)(XE / 4);
    ca.src[2] = (const float*)d_in[2]; ca.dst[2] = xb + 2L * XE; ca.n4[2] = (int)(XE / 4);
    ca.src[3] = (const float*)d_in[3]; ca.dst[3] = wb;           ca.n4[3] = (int)(WE / 4);
    ca.src[4] = (const float*)d_in[5]; ca.dst[4] = wb + WE;      ca.n4[4] = (int)(WE / 4);
    ca.src[5] = (const float*)d_in[7]; ca.dst[5] = wb + 2L * WE; ca.n4[5] = (int)(WE / 4);
    ca.src[6] = (const float*)d_in[9]; ca.dst[6] = wb + 3L * WE; ca.n4[6] = (int)(WE / 4);

    hipLaunchKernelGGL(convert_kernel, dim3(512, 7), dim3(256), 0, stream, ca);

    hipLaunchKernelGGL(proj_kernel, dim3(8, 32, 3), dim3(256), 0, stream,
                       xb, wb, (const float*)d_in[4], (const float*)d_in[6],
                       (const float*)d_in[8], qkv);

    hipLaunchKernelGGL(attn_kernel, dim3(16, 32), dim3(512), 0, stream,
                       qkv, qkv + XE, qkv + 2L * XE, ob);

    hipLaunchKernelGGL(out_kernel, dim3(8, 32), dim3(256), 0, stream,
                       ob, wb + 3L * WE, (const float*)d_in[10], (float*)d_out);
}